// Round 16
// baseline (79.740 us; speedup 1.0000x reference)
//
#include <hip/hip_runtime.h>

#define NTHR 512
#define TB 32

typedef __attribute__((ext_vector_type(8))) short bf16x8;
typedef __attribute__((ext_vector_type(16))) float f32x16;
typedef __attribute__((ext_vector_type(4))) float f32v4;
typedef float4 f4;
typedef unsigned short u16;

__device__ __forceinline__ u16 f2b(float x) {
  union { float f; unsigned u; } v; v.f = x;
  unsigned r = (v.u + 0x7fffu + ((v.u >> 16) & 1u)) >> 16;
  return (u16)r;
}
__device__ __forceinline__ float b2f(u16 u) {
  union { unsigned u; float f; } v; v.u = ((unsigned)u) << 16;
  return v.f;
}
__device__ __forceinline__ unsigned pack2(float a, float b) {
  return (unsigned)f2b(a) | ((unsigned)f2b(b) << 16);
}
__device__ __forceinline__ unsigned cvtpk(float lo, float hi) {
  unsigned r;
  asm("v_cvt_pk_bf16_f32 %0, %1, %2" : "=v"(r) : "v"(lo), "v"(hi));
  return r;
}
__device__ __forceinline__ f4 ntload4(const float* p) {
  f32v4 v = __builtin_nontemporal_load((const f32v4*)p);
  return make_float4(v.x, v.y, v.z, v.w);
}

#define MFMA32(A, B, C) __builtin_amdgcn_mfma_f32_32x32x16_bf16(A, B, C, 0, 0, 0)

// ---------------- prep: 32x32x16-fragment-ordered bf16 weights (verified) ------
extern "C" __global__ void hosvd_prep(const float* __restrict__ U,
                                      const float* __restrict__ T,
                                      const float* __restrict__ UO,
                                      unsigned* __restrict__ ws32) {
  int id = blockIdx.x * 256 + threadIdx.x;
  if (id < 102400) {                      // BTf: 25600 frags * 4 u32
    int j2 = id & 3, frag = id >> 2;
    int l = frag & 63, f2 = frag >> 6;    // f2 = (a*20+ks)*5+nt
    int nt = f2 % 5, aks = f2 / 5;
    int ks = aks % 20, a = aks / 20;
    int n = nt * 32 + (l & 31);
    int p = n >> 4, s = n & 15;
    float v[2];
    #pragma unroll
    for (int j = 0; j < 2; ++j) {
      int kp = ks * 16 + (l >> 5) * 8 + j2 * 2 + j;
      int q = (unsigned)kp / 18u, r = kp - q * 18;
      float x = 0.f;
      if (p <= 8 && q <= 16 && r <= 16)
        x = T[(((a * 9 + p) * 17 + q) * 17 + r) * 16 + s];
      v[j] = x;
    }
    ws32[id] = pack2(v[0], v[1]);
  } else if (id < 118784) {               // UcTf: 4096 frags * 4 u32
    int rel = id - 102400;
    int j2 = rel & 3, frag = rel >> 2;
    int l = frag & 63, f2 = frag >> 6;    // f2 = (c*16+ks)*2+nt
    int nt = f2 & 1, ks = (f2 >> 1) & 15, c = f2 >> 5;
    int n = nt * 32 + (l & 31);
    int a = n >> 4, rr = n & 15;
    int k = ks * 16 + (l >> 5) * 8 + j2 * 2;
    float v0 = U[((c * 4 + a) * 256 + k + 0) * 16 + rr];
    float v1 = U[((c * 4 + a) * 256 + k + 1) * 16 + rr];
    ws32[id] = pack2(v0, v1);
  } else if (id < 126976) {               // UOTf: 2048 frags * 4 u32
    int rel = id - 118784;
    int j2 = rel & 3, frag = rel >> 2;
    int l = frag & 63, f2 = frag >> 6;    // f2 = a*8+ht
    int ht = f2 & 7, a = f2 >> 3;
    int h = ht * 32 + (l & 31);
    int k = (l >> 5) * 8 + j2 * 2;        // < 16 always
    float v0 = UO[(a * 16 + k + 0) * 256 + h];
    float v1 = UO[(a * 16 + k + 1) * 256 + h];
    ws32[id] = pack2(v0, v1);
  }
}

// ---------------- main fused kernel: 2-tile persistent pipeline ----------------
// r10 arithmetic verbatim; loop shell processes tile it=0,1 (item base
// blockIdx*32 + it*half). Tile-1 nh/te are loaded into REGISTERS at the start
// of tile-0's core phase (latency + tile-0 store burst hide under compute).
// LDS 56704 B (1 block/CU at grid 256):
//  s_u   [20800] u16: nh [32][520] | Ut f32[1024] @16640 | te f32[1056] @18688
//        post-barrier-2 alias: s_red f32[2][4][32][16] (16 KB) at byte 0
//  s_ch  [32][164] u16: h[row][c*80+a*20+idx]; idx16=1.0, idx17..19=0 sentinels
//  s_tpt [36][32] f32: tp transposed [a*9+p][row]; p=8 row = 1.0 sentinel
extern "C" __global__ __launch_bounds__(NTHR, 2)
void hosvd_main(const float* __restrict__ nh, const float* __restrict__ te,
                const float* __restrict__ bw, const float* __restrict__ Ut,
                const float* __restrict__ bt, const float* __restrict__ bO,
                const u16* __restrict__ BTf, const u16* __restrict__ UcTf,
                const u16* __restrict__ UOTf, float* __restrict__ out,
                int half) {
  __shared__ __align__(16) u16   s_u[20800];
  __shared__ __align__(16) u16   s_ch[TB * 164];
  __shared__ __align__(16) float s_tpt[36 * 32];

  const int t = threadIdx.x;
  const int w = t >> 6, l = t & 63;
  const int l31 = l & 31, hi = l >> 5;

  float* UtL = (float*)&s_u[16640];
  float* teL = (float*)&s_u[18688];
  float* s_redf = (float*)s_u;          // post-barrier-2 alias (16 KB)

  //---- one-time sentinels (persist across both tiles) ----
  if (t < 256) {  // s_ch idx 16..19 = {1.0, 0, 0, 0} per (row,c,a)
    const int row = t >> 3, cc = (t >> 2) & 1, aa = t & 3;
    *(uint2*)&s_ch[row * 164 + cc * 80 + aa * 20 + 16] = make_uint2(0x3F80u, 0u);
  }
  if (t < 128) {  // s_tpt p=8 row = 1.0
    const int aa = t >> 5, row = t & 31;
    s_tpt[(aa * 9 + 8) * 32 + row] = 1.0f;
  }

  f4 Rnh[8];   // next-tile nh prefetch (32 VGPR)
  f4 Rte;      // next-tile te prefetch (threads 0..255)

  for (int it = 0; it < 2; ++it) {
    const int ib0 = blockIdx.x * TB + it * half;

    //---- stage: te -> teL, Ut -> UtL (it=0), nh -> s_u bf16 [32][520] ----
    if (it == 0) {
      if (t < 256) {
        const int row = t >> 3, k4 = t & 7;
        f4 v = ntload4(&te[(size_t)(ib0 + row) * 32 + k4 * 4]);
        float* d = &teL[row * 33 + k4 * 4];
        d[0] = v.x; d[1] = v.y; d[2] = v.z; d[3] = v.w;
      } else {
        const int j = t - 256;
        *(f4*)&UtL[j * 4] = *(const f4*)&Ut[j * 4];
      }
      for (int lp = t; lp < 4096; lp += NTHR) {
        const int row = lp >> 7, rem = lp & 127;
        const int c = rem >> 6, k0 = (rem & 63) * 4;
        f4 v = ntload4(&nh[((size_t)(ib0 + row) * 2 + c) * 256 + k0]);
        *(uint2*)&s_u[row * 520 + c * 256 + k0] =
            make_uint2(cvtpk(v.x, v.y), cvtpk(v.z, v.w));
      }
    } else {
      // from prefetch registers (loaded during tile-0 core)
      if (t < 256) {
        const int row = t >> 3, k4 = t & 7;
        float* d = &teL[row * 33 + k4 * 4];
        d[0] = Rte.x; d[1] = Rte.y; d[2] = Rte.z; d[3] = Rte.w;
      }
      #pragma unroll
      for (int k2 = 0; k2 < 8; ++k2) {
        const int lp = t + k2 * NTHR;
        const int row = lp >> 7, rem = lp & 127;
        const int c = rem >> 6, k0 = (rem & 63) * 4;
        f4 v = Rnh[k2];
        *(uint2*)&s_u[row * 520 + c * 256 + k0] =
            make_uint2(cvtpk(v.x, v.y), cvtpk(v.z, v.w));
      }
    }
    __syncthreads();   // barrier 1

    //---- Phase C (waves 0-3) || Phase B (waves 4-7) ----
    if (w < 4) {
      const int c = w & 1, nt2 = w >> 1;
      f32x16 accC = {0.f, 0.f, 0.f, 0.f, 0.f, 0.f, 0.f, 0.f,
                     0.f, 0.f, 0.f, 0.f, 0.f, 0.f, 0.f, 0.f};
      #pragma unroll
      for (int ks = 0; ks < 16; ++ks) {
        bf16x8 Av = *(const bf16x8*)&s_u[l31 * 520 + c * 256 + ks * 16 + hi * 8];
        bf16x8 Bv = *(const bf16x8*)
            &UcTf[(size_t)(((c * 16 + ks) * 2 + nt2) * 64 + l) * 8];
        accC = MFMA32(Av, Bv, accC);
      }
      const int n = nt2 * 32 + l31;
      const int ca = n >> 4, rr = n & 15;
      const float bias = bw[(c * 4 + ca) * 16 + rr];
      #pragma unroll
      for (int reg = 0; reg < 16; ++reg) {
        const int row = (reg & 3) + 8 * (reg >> 2) + 4 * hi;
        s_ch[row * 164 + c * 80 + ca * 20 + rr] = f2b(accC[reg] + bias);
      }
    } else {
      const int t2 = t - 256;
      const int i = t2 >> 3, off = (t2 & 7) * 4;
      float ac0 = bt[off], ac1 = bt[off + 1], ac2 = bt[off + 2], ac3 = bt[off + 3];
      #pragma unroll
      for (int k = 0; k < 32; ++k) {
        const float tv = teL[i * 33 + k];
        f4 u = *(const f4*)&UtL[k * 32 + off];
        ac0 = fmaf(tv, u.x, ac0);
        ac1 = fmaf(tv, u.y, ac1);
        ac2 = fmaf(tv, u.z, ac2);
        ac3 = fmaf(tv, u.w, ac3);
      }
      #pragma unroll
      for (int jj = 0; jj < 4; ++jj) {
        const int o2 = off + jj;
        const float v = (jj == 0) ? ac0 : (jj == 1) ? ac1 : (jj == 2) ? ac2 : ac3;
        s_tpt[((o2 >> 3) * 9 + (o2 & 7)) * 32 + i] = v;
      }
    }
    __syncthreads();   // barrier 2: s_ch + s_tpt ready; s_u nh region dead

    //---- prefetch next tile's nh/te into registers (tile 0 only) ----
    if (it == 0) {
      const int ib1 = blockIdx.x * TB + half;
      #pragma unroll
      for (int k2 = 0; k2 < 8; ++k2) {
        const int lp = t + k2 * NTHR;
        const int row = lp >> 7, rem = lp & 127;
        const int c = rem >> 6, k0 = (rem & 63) * 4;
        Rnh[k2] = ntload4(&nh[((size_t)(ib1 + row) * 2 + c) * 256 + k0]);
      }
      if (t < 256)
        Rte = ntload4(&te[(size_t)(ib1 + (t >> 3)) * 32 + (t & 7) * 4]);
    }

    //---- Core: wave (a, kh) — 10 ksteps, M=32, N=160(5 tiles), in-reg A ----
    {
      const int a = w & 3, kh = w >> 2;
      const u16* h1g = &s_ch[l31 * 164 + a * 20];
      const u16* h2g = h1g + 80;

      f32x16 acc[5];
      #pragma unroll
      for (int nt = 0; nt < 5; ++nt)
        acc[nt] = (f32x16){0.f, 0.f, 0.f, 0.f, 0.f, 0.f, 0.f, 0.f,
                           0.f, 0.f, 0.f, 0.f, 0.f, 0.f, 0.f, 0.f};

      __builtin_amdgcn_s_setprio(1);
      #pragma unroll
      for (int ks2 = 0; ks2 < 10; ++ks2) {
        const int ks = kh * 10 + ks2;
        const u16* bp = &BTf[(size_t)((a * 20 + ks) * 5) * 512 + l * 8];
        bf16x8 B0 = *(const bf16x8*)(bp + 0 * 512);
        bf16x8 B1 = *(const bf16x8*)(bp + 1 * 512);
        bf16x8 B2 = *(const bf16x8*)(bp + 2 * 512);
        bf16x8 B3 = *(const bf16x8*)(bp + 3 * 512);
        bf16x8 B4 = *(const bf16x8*)(bp + 4 * 512);

        // A frag: O[row=l31][k'], k' = ks*16 + hi*8 + j
        const int k0 = ks * 16 + hi * 8;
        const unsigned q0 = (unsigned)k0 / 18u;
        const int r0 = k0 - (int)q0 * 18;
        const int brk = 18 - r0;
        const float h1a = b2f(h1g[q0]);
        const float h1b = b2f(h1g[q0 + 1]);   // slots <=19 zero-init'd
        float hv[8];
        #pragma unroll
        for (int j = 0; j < 8; ++j) {
          int rr = r0 + j;
          rr = (rr >= 18) ? rr - 18 : rr;
          const float h2v = b2f(h2g[rr]);
          hv[j] = ((j < brk) ? h1a : h1b) * h2v;
        }
        union { unsigned u[4]; bf16x8 v; } Au;
        Au.u[0] = cvtpk(hv[0], hv[1]);
        Au.u[1] = cvtpk(hv[2], hv[3]);
        Au.u[2] = cvtpk(hv[4], hv[5]);
        Au.u[3] = cvtpk(hv[6], hv[7]);

        acc[0] = MFMA32(Au.v, B0, acc[0]);
        acc[1] = MFMA32(Au.v, B1, acc[1]);
        acc[2] = MFMA32(Au.v, B2, acc[2]);
        acc[3] = MFMA32(Au.v, B3, acc[3]);
        acc[4] = MFMA32(Au.v, B4, acc[4]);
      }
      __builtin_amdgcn_s_setprio(0);

      //-- per-lane h0 fold (col -> p), then parity combine via shfl_xor(16) --
      float gp[16];
      #pragma unroll
      for (int reg = 0; reg < 16; ++reg) gp[reg] = 0.f;
      #pragma unroll
      for (int nt = 0; nt < 5; ++nt) {
        int pp = nt * 2 + (l31 >> 4);
        if (pp > 8) pp = 8;                  // p=9 pad: acc cols are zero
        const float* tpb = &s_tpt[(a * 9 + pp) * 32 + 4 * hi];
        f4 t0 = *(const f4*)&tpb[0];
        f4 t1 = *(const f4*)&tpb[8];
        f4 t2 = *(const f4*)&tpb[16];
        f4 t3 = *(const f4*)&tpb[24];
        gp[0]  = fmaf(t0.x, acc[nt][0],  gp[0]);
        gp[1]  = fmaf(t0.y, acc[nt][1],  gp[1]);
        gp[2]  = fmaf(t0.z, acc[nt][2],  gp[2]);
        gp[3]  = fmaf(t0.w, acc[nt][3],  gp[3]);
        gp[4]  = fmaf(t1.x, acc[nt][4],  gp[4]);
        gp[5]  = fmaf(t1.y, acc[nt][5],  gp[5]);
        gp[6]  = fmaf(t1.z, acc[nt][6],  gp[6]);
        gp[7]  = fmaf(t1.w, acc[nt][7],  gp[7]);
        gp[8]  = fmaf(t2.x, acc[nt][8],  gp[8]);
        gp[9]  = fmaf(t2.y, acc[nt][9],  gp[9]);
        gp[10] = fmaf(t2.z, acc[nt][10], gp[10]);
        gp[11] = fmaf(t2.w, acc[nt][11], gp[11]);
        gp[12] = fmaf(t3.x, acc[nt][12], gp[12]);
        gp[13] = fmaf(t3.y, acc[nt][13], gp[13]);
        gp[14] = fmaf(t3.z, acc[nt][14], gp[14]);
        gp[15] = fmaf(t3.w, acc[nt][15], gp[15]);
      }
      #pragma unroll
      for (int reg = 0; reg < 16; ++reg)
        gp[reg] += __shfl_xor(gp[reg], 16, 64);
      if ((l & 16) == 0) {
        const int s = l & 15;
        #pragma unroll
        for (int reg = 0; reg < 16; ++reg) {
          const int row = (reg & 3) + 8 * (reg >> 2) + 4 * hi;
          s_redf[((kh * 4 + a) * 32 + row) * 16 + s] = gp[reg];
        }
      }
    }
    __syncthreads();   // barrier 3: s_red ready

    //---- Phase E: wave = ht (32 cols), K=16 exact; K-reduce in A-build ----
    {
      #pragma unroll
      for (int a = 0; a < 4; ++a) {
        const float* r0p = &s_redf[((0 + a) * 32 + l31) * 16 + hi * 8];
        const float* r1p = &s_redf[((4 + a) * 32 + l31) * 16 + hi * 8];
        f4 xa = *(const f4*)&r0p[0], xb = *(const f4*)&r0p[4];
        f4 ya = *(const f4*)&r1p[0], yb = *(const f4*)&r1p[4];
        union { unsigned u[4]; bf16x8 v; } Au;
        Au.u[0] = cvtpk(xa.x + ya.x, xa.y + ya.y);
        Au.u[1] = cvtpk(xa.z + ya.z, xa.w + ya.w);
        Au.u[2] = cvtpk(xb.x + yb.x, xb.y + yb.y);
        Au.u[3] = cvtpk(xb.z + yb.z, xb.w + yb.w);
        bf16x8 Bv = *(const bf16x8*)&UOTf[((size_t)(a * 8 + w) * 64 + l) * 8];
        const int h = w * 32 + l31;
        const float bias = bO[a * 256 + h];
        f32x16 accE = {bias, bias, bias, bias, bias, bias, bias, bias,
                       bias, bias, bias, bias, bias, bias, bias, bias};
        accE = MFMA32(Au.v, Bv, accE);
        #pragma unroll
        for (int reg = 0; reg < 16; ++reg) {
          const int row = (reg & 3) + 8 * (reg >> 2) + 4 * hi;
          __builtin_nontemporal_store(
              accE[reg], &out[(size_t)(ib0 + row) * 1024 + a * 256 + h]);
        }
      }
    }
    if (it == 0) __syncthreads();   // barrier 4: s_redf reads done before
                                    // tile-1 stage overwrites s_u
  }
}

extern "C" void kernel_launch(void* const* d_in, const int* in_sizes, int n_in,
                              void* d_out, int out_size, void* d_ws, size_t ws_size,
                              hipStream_t stream) {
  const float* nh = (const float*)d_in[0];
  const float* te = (const float*)d_in[1];
  const float* U  = (const float*)d_in[2];
  const float* bw = (const float*)d_in[3];
  const float* Ut = (const float*)d_in[4];
  const float* bt = (const float*)d_in[5];
  const float* T  = (const float*)d_in[6];
  const float* UO = (const float*)d_in[7];
  const float* bO = (const float*)d_in[8];
  float* out = (float*)d_out;

  unsigned* ws32 = (unsigned*)d_ws;
  hipLaunchKernelGGL(hosvd_prep, dim3(496), dim3(256), 0, stream, U, T, UO, ws32);

  const u16* BTf  = (const u16*)d_ws;         // 204800 u16
  const u16* UcTf = BTf + 204800;             // 32768 u16
  const u16* UOTf = UcTf + 32768;             // 16384 u16

  const int bs = in_sizes[0] / 512;           // (BS,2,256)
  const int half = bs / 2;
  hipLaunchKernelGGL(hosvd_main, dim3(half / TB), dim3(NTHR), 0, stream,
                     nh, te, bw, Ut, bt, bO, BTf, UcTf, UOTf, out, half);
}

// Round 17
// 39.315 us; speedup vs baseline: 2.0283x; 2.0283x over previous
//
#include <hip/hip_runtime.h>

#define NTHR 512
#define TB 32

typedef __attribute__((ext_vector_type(8))) short bf16x8;
typedef __attribute__((ext_vector_type(16))) float f32x16;
typedef __attribute__((ext_vector_type(4))) float f32v4;
typedef float4 f4;
typedef unsigned short u16;

__device__ __forceinline__ u16 f2b(float x) {
  union { float f; unsigned u; } v; v.f = x;
  unsigned r = (v.u + 0x7fffu + ((v.u >> 16) & 1u)) >> 16;
  return (u16)r;
}
__device__ __forceinline__ float b2f(u16 u) {
  union { unsigned u; float f; } v; v.u = ((unsigned)u) << 16;
  return v.f;
}
__device__ __forceinline__ unsigned pack2(float a, float b) {
  return (unsigned)f2b(a) | ((unsigned)f2b(b) << 16);
}
__device__ __forceinline__ unsigned cvtpk(float lo, float hi) {
  unsigned r;
  asm("v_cvt_pk_bf16_f32 %0, %1, %2" : "=v"(r) : "v"(lo), "v"(hi));
  return r;
}
// non-temporal 16B load (streaming data: nh, te)
__device__ __forceinline__ f4 ntload4(const float* p) {
  f32v4 v = __builtin_nontemporal_load((const f32v4*)p);
  return make_float4(v.x, v.y, v.z, v.w);
}

#define MFMA32(A, B, C) __builtin_amdgcn_mfma_f32_32x32x16_bf16(A, B, C, 0, 0, 0)

// ---------------- prep: 32x32x16-fragment-ordered bf16 weights ----------------
// All frags: lane l, col n = base + (l&31), k = kstep*16 + (l>>5)*8 + j (j=0..7).
// BTf : frag = (a*20+ks)*5+nt, n = nt*32+(l&31) -> (p=n>>4, s=n&15);
//       k' = ks*16+(l>>5)*8+j -> (q=k'/18, r=k'%18); zero if p>8 | q>16 | r>16.
// UcTf: frag = (c*16+ks)*2+nt, n -> (a=n>>4, r=n&15); k = ks*16+(l>>5)*8+j.
// UOTf: frag = a*8+ht, col h = ht*32+(l&31); k = (l>>5)*8+j (K=16 exact).
extern "C" __global__ void hosvd_prep(const float* __restrict__ U,
                                      const float* __restrict__ T,
                                      const float* __restrict__ UO,
                                      unsigned* __restrict__ ws32) {
  int id = blockIdx.x * 256 + threadIdx.x;
  if (id < 102400) {                      // BTf: 25600 frags * 4 u32
    int j2 = id & 3, frag = id >> 2;
    int l = frag & 63, f2 = frag >> 6;    // f2 = (a*20+ks)*5+nt
    int nt = f2 % 5, aks = f2 / 5;
    int ks = aks % 20, a = aks / 20;
    int n = nt * 32 + (l & 31);
    int p = n >> 4, s = n & 15;
    float v[2];
    #pragma unroll
    for (int j = 0; j < 2; ++j) {
      int kp = ks * 16 + (l >> 5) * 8 + j2 * 2 + j;
      int q = (unsigned)kp / 18u, r = kp - q * 18;
      float x = 0.f;
      if (p <= 8 && q <= 16 && r <= 16)
        x = T[(((a * 9 + p) * 17 + q) * 17 + r) * 16 + s];
      v[j] = x;
    }
    ws32[id] = pack2(v[0], v[1]);
  } else if (id < 118784) {               // UcTf: 4096 frags * 4 u32
    int rel = id - 102400;
    int j2 = rel & 3, frag = rel >> 2;
    int l = frag & 63, f2 = frag >> 6;    // f2 = (c*16+ks)*2+nt
    int nt = f2 & 1, ks = (f2 >> 1) & 15, c = f2 >> 5;
    int n = nt * 32 + (l & 31);
    int a = n >> 4, rr = n & 15;
    int k = ks * 16 + (l >> 5) * 8 + j2 * 2;
    float v0 = U[((c * 4 + a) * 256 + k + 0) * 16 + rr];
    float v1 = U[((c * 4 + a) * 256 + k + 1) * 16 + rr];
    ws32[id] = pack2(v0, v1);
  } else if (id < 126976) {               // UOTf: 2048 frags * 4 u32
    int rel = id - 118784;
    int j2 = rel & 3, frag = rel >> 2;
    int l = frag & 63, f2 = frag >> 6;    // f2 = a*8+ht
    int ht = f2 & 7, a = f2 >> 3;
    int h = ht * 32 + (l & 31);
    int k = (l >> 5) * 8 + j2 * 2;        // < 16 always
    float v0 = UO[(a * 16 + k + 0) * 256 + h];
    float v1 = UO[(a * 16 + k + 1) * 256 + h];
    ws32[id] = pack2(v0, v1);
  }
}

// ---------------- main fused kernel ----------------
// r10 structure (3-barrier skeleton, 32x32x16 MFMA), + non-temporal hints on
// streaming accesses (nh/te loads, out stores) to keep the weight set L2-hot.
// LDS 56704 B:
//  s_u   [20800] u16: nh [32][520] | Ut f32[1024] @16640 | te f32[1056] @18688
//        post-barrier-2 alias: s_red f32[2][4][32][16] (16 KB) at byte 0
//  s_ch  [32][164] u16: h[row][c*80+a*20+idx]; idx16=1.0, idx17..19=0 sentinels
//  s_tpt [36][32] f32: tp transposed [a*9+p][row]; p=8 row = 1.0 sentinel
extern "C" __global__ __launch_bounds__(NTHR, 4)
void hosvd_main(const float* __restrict__ nh, const float* __restrict__ te,
                const float* __restrict__ bw, const float* __restrict__ Ut,
                const float* __restrict__ bt, const float* __restrict__ bO,
                const u16* __restrict__ BTf, const u16* __restrict__ UcTf,
                const u16* __restrict__ UOTf, float* __restrict__ out) {
  __shared__ __align__(16) u16   s_u[20800];
  __shared__ __align__(16) u16   s_ch[TB * 164];
  __shared__ __align__(16) float s_tpt[36 * 32];

  const int t = threadIdx.x;
  const int ib0 = blockIdx.x * TB;
  const int w = t >> 6, l = t & 63;
  const int l31 = l & 31, hi = l >> 5;

  float* UtL = (float*)&s_u[16640];
  float* teL = (float*)&s_u[18688];
  float* s_redf = (float*)s_u;          // post-barrier-2 alias (16 KB)

  //---- sentinels ----
  if (t < 256) {  // s_ch idx 16..19 = {1.0, 0, 0, 0} per (row,c,a)
    const int row = t >> 3, cc = (t >> 2) & 1, aa = t & 3;
    *(uint2*)&s_ch[row * 164 + cc * 80 + aa * 20 + 16] = make_uint2(0x3F80u, 0u);
  }
  if (t < 128) {  // s_tpt p=8 row = 1.0
    const int aa = t >> 5, row = t & 31;
    s_tpt[(aa * 9 + 8) * 32 + row] = 1.0f;
  }

  //---- stage: te -> teL, Ut -> UtL, nh -> s_u bf16 [32][520] ----
  if (t < 256) {
    const int row = t >> 3, k4 = t & 7;
    f4 v = ntload4(&te[(size_t)(ib0 + row) * 32 + k4 * 4]);
    float* d = &teL[row * 33 + k4 * 4];
    d[0] = v.x; d[1] = v.y; d[2] = v.z; d[3] = v.w;
  } else {
    const int j = t - 256;
    *(f4*)&UtL[j * 4] = *(const f4*)&Ut[j * 4];
  }
  for (int lp = t; lp < 4096; lp += NTHR) {
    const int row = lp >> 7, rem = lp & 127;
    const int c = rem >> 6, k0 = (rem & 63) * 4;
    f4 v = ntload4(&nh[((size_t)(ib0 + row) * 2 + c) * 256 + k0]);
    *(uint2*)&s_u[row * 520 + c * 256 + k0] =
        make_uint2(cvtpk(v.x, v.y), cvtpk(v.z, v.w));
  }
  __syncthreads();   // barrier 1

  //---- Phase C (waves 0-3) || Phase B (waves 4-7) ----
  if (w < 4) {
    const int c = w & 1, nt2 = w >> 1;
    f32x16 accC = {0.f, 0.f, 0.f, 0.f, 0.f, 0.f, 0.f, 0.f,
                   0.f, 0.f, 0.f, 0.f, 0.f, 0.f, 0.f, 0.f};
    #pragma unroll
    for (int ks = 0; ks < 16; ++ks) {
      bf16x8 Av = *(const bf16x8*)&s_u[l31 * 520 + c * 256 + ks * 16 + hi * 8];
      bf16x8 Bv = *(const bf16x8*)
          &UcTf[(size_t)(((c * 16 + ks) * 2 + nt2) * 64 + l) * 8];
      accC = MFMA32(Av, Bv, accC);
    }
    const int n = nt2 * 32 + l31;
    const int ca = n >> 4, rr = n & 15;
    const float bias = bw[(c * 4 + ca) * 16 + rr];
    #pragma unroll
    for (int reg = 0; reg < 16; ++reg) {
      const int row = (reg & 3) + 8 * (reg >> 2) + 4 * hi;
      s_ch[row * 164 + c * 80 + ca * 20 + rr] = f2b(accC[reg] + bias);
    }
  } else {
    const int t2 = t - 256;
    const int i = t2 >> 3, off = (t2 & 7) * 4;
    float ac0 = bt[off], ac1 = bt[off + 1], ac2 = bt[off + 2], ac3 = bt[off + 3];
    #pragma unroll
    for (int k = 0; k < 32; ++k) {
      const float tv = teL[i * 33 + k];
      f4 u = *(const f4*)&UtL[k * 32 + off];
      ac0 = fmaf(tv, u.x, ac0);
      ac1 = fmaf(tv, u.y, ac1);
      ac2 = fmaf(tv, u.z, ac2);
      ac3 = fmaf(tv, u.w, ac3);
    }
    #pragma unroll
    for (int jj = 0; jj < 4; ++jj) {
      const int o2 = off + jj;
      const float v = (jj == 0) ? ac0 : (jj == 1) ? ac1 : (jj == 2) ? ac2 : ac3;
      s_tpt[((o2 >> 3) * 9 + (o2 & 7)) * 32 + i] = v;
    }
  }
  __syncthreads();   // barrier 2: s_ch + s_tpt ready; s_u nh region dead

  //---- Core: wave (a, kh) — 10 ksteps, M=32, N=160(5 tiles), in-reg A ----
  {
    const int a = w & 3, kh = w >> 2;
    const u16* h1g = &s_ch[l31 * 164 + a * 20];
    const u16* h2g = h1g + 80;

    f32x16 acc[5];
    #pragma unroll
    for (int nt = 0; nt < 5; ++nt)
      acc[nt] = (f32x16){0.f, 0.f, 0.f, 0.f, 0.f, 0.f, 0.f, 0.f,
                         0.f, 0.f, 0.f, 0.f, 0.f, 0.f, 0.f, 0.f};

    __builtin_amdgcn_s_setprio(1);
    #pragma unroll
    for (int ks2 = 0; ks2 < 10; ++ks2) {
      const int ks = kh * 10 + ks2;
      const u16* bp = &BTf[(size_t)((a * 20 + ks) * 5) * 512 + l * 8];
      bf16x8 B0 = *(const bf16x8*)(bp + 0 * 512);
      bf16x8 B1 = *(const bf16x8*)(bp + 1 * 512);
      bf16x8 B2 = *(const bf16x8*)(bp + 2 * 512);
      bf16x8 B3 = *(const bf16x8*)(bp + 3 * 512);
      bf16x8 B4 = *(const bf16x8*)(bp + 4 * 512);

      // A frag: O[row=l31][k'], k' = ks*16 + hi*8 + j
      const int k0 = ks * 16 + hi * 8;
      const unsigned q0 = (unsigned)k0 / 18u;
      const int r0 = k0 - (int)q0 * 18;
      const int brk = 18 - r0;
      const float h1a = b2f(h1g[q0]);
      const float h1b = b2f(h1g[q0 + 1]);   // slots <=19 zero-init'd
      float hv[8];
      #pragma unroll
      for (int j = 0; j < 8; ++j) {
        int rr = r0 + j;
        rr = (rr >= 18) ? rr - 18 : rr;
        const float h2v = b2f(h2g[rr]);
        hv[j] = ((j < brk) ? h1a : h1b) * h2v;
      }
      union { unsigned u[4]; bf16x8 v; } Au;
      Au.u[0] = cvtpk(hv[0], hv[1]);
      Au.u[1] = cvtpk(hv[2], hv[3]);
      Au.u[2] = cvtpk(hv[4], hv[5]);
      Au.u[3] = cvtpk(hv[6], hv[7]);

      acc[0] = MFMA32(Au.v, B0, acc[0]);
      acc[1] = MFMA32(Au.v, B1, acc[1]);
      acc[2] = MFMA32(Au.v, B2, acc[2]);
      acc[3] = MFMA32(Au.v, B3, acc[3]);
      acc[4] = MFMA32(Au.v, B4, acc[4]);
    }
    __builtin_amdgcn_s_setprio(0);

    //-- per-lane h0 fold (col -> p), then parity combine via shfl_xor(16) --
    float gp[16];
    #pragma unroll
    for (int reg = 0; reg < 16; ++reg) gp[reg] = 0.f;
    #pragma unroll
    for (int nt = 0; nt < 5; ++nt) {
      int pp = nt * 2 + (l31 >> 4);
      if (pp > 8) pp = 8;                  // p=9 pad: acc cols are zero
      const float* tpb = &s_tpt[(a * 9 + pp) * 32 + 4 * hi];
      f4 t0 = *(const f4*)&tpb[0];
      f4 t1 = *(const f4*)&tpb[8];
      f4 t2 = *(const f4*)&tpb[16];
      f4 t3 = *(const f4*)&tpb[24];
      gp[0]  = fmaf(t0.x, acc[nt][0],  gp[0]);
      gp[1]  = fmaf(t0.y, acc[nt][1],  gp[1]);
      gp[2]  = fmaf(t0.z, acc[nt][2],  gp[2]);
      gp[3]  = fmaf(t0.w, acc[nt][3],  gp[3]);
      gp[4]  = fmaf(t1.x, acc[nt][4],  gp[4]);
      gp[5]  = fmaf(t1.y, acc[nt][5],  gp[5]);
      gp[6]  = fmaf(t1.z, acc[nt][6],  gp[6]);
      gp[7]  = fmaf(t1.w, acc[nt][7],  gp[7]);
      gp[8]  = fmaf(t2.x, acc[nt][8],  gp[8]);
      gp[9]  = fmaf(t2.y, acc[nt][9],  gp[9]);
      gp[10] = fmaf(t2.z, acc[nt][10], gp[10]);
      gp[11] = fmaf(t2.w, acc[nt][11], gp[11]);
      gp[12] = fmaf(t3.x, acc[nt][12], gp[12]);
      gp[13] = fmaf(t3.y, acc[nt][13], gp[13]);
      gp[14] = fmaf(t3.z, acc[nt][14], gp[14]);
      gp[15] = fmaf(t3.w, acc[nt][15], gp[15]);
    }
    #pragma unroll
    for (int reg = 0; reg < 16; ++reg)
      gp[reg] += __shfl_xor(gp[reg], 16, 64);
    if ((l & 16) == 0) {
      const int s = l & 15;
      #pragma unroll
      for (int reg = 0; reg < 16; ++reg) {
        const int row = (reg & 3) + 8 * (reg >> 2) + 4 * hi;
        s_redf[((kh * 4 + a) * 32 + row) * 16 + s] = gp[reg];
      }
    }
  }
  __syncthreads();   // barrier 3: s_red ready

  //---- Phase E: wave = ht (32 cols), K=16 exact; K-reduce fused in A-build ----
  {
    #pragma unroll
    for (int a = 0; a < 4; ++a) {
      const float* r0p = &s_redf[((0 + a) * 32 + l31) * 16 + hi * 8];
      const float* r1p = &s_redf[((4 + a) * 32 + l31) * 16 + hi * 8];
      f4 xa = *(const f4*)&r0p[0], xb = *(const f4*)&r0p[4];
      f4 ya = *(const f4*)&r1p[0], yb = *(const f4*)&r1p[4];
      union { unsigned u[4]; bf16x8 v; } Au;
      Au.u[0] = cvtpk(xa.x + ya.x, xa.y + ya.y);
      Au.u[1] = cvtpk(xa.z + ya.z, xa.w + ya.w);
      Au.u[2] = cvtpk(xb.x + yb.x, xb.y + yb.y);
      Au.u[3] = cvtpk(xb.z + yb.z, xb.w + yb.w);
      bf16x8 Bv = *(const bf16x8*)&UOTf[((size_t)(a * 8 + w) * 64 + l) * 8];
      const int h = w * 32 + l31;
      const float bias = bO[a * 256 + h];
      f32x16 accE = {bias, bias, bias, bias, bias, bias, bias, bias,
                     bias, bias, bias, bias, bias, bias, bias, bias};
      accE = MFMA32(Au.v, Bv, accE);
      #pragma unroll
      for (int reg = 0; reg < 16; ++reg) {
        const int row = (reg & 3) + 8 * (reg >> 2) + 4 * hi;
        __builtin_nontemporal_store(
            accE[reg], &out[(size_t)(ib0 + row) * 1024 + a * 256 + h]);
      }
    }
  }
}

extern "C" void kernel_launch(void* const* d_in, const int* in_sizes, int n_in,
                              void* d_out, int out_size, void* d_ws, size_t ws_size,
                              hipStream_t stream) {
  const float* nh = (const float*)d_in[0];
  const float* te = (const float*)d_in[1];
  const float* U  = (const float*)d_in[2];
  const float* bw = (const float*)d_in[3];
  const float* Ut = (const float*)d_in[4];
  const float* bt = (const float*)d_in[5];
  const float* T  = (const float*)d_in[6];
  const float* UO = (const float*)d_in[7];
  const float* bO = (const float*)d_in[8];
  float* out = (float*)d_out;

  unsigned* ws32 = (unsigned*)d_ws;
  hipLaunchKernelGGL(hosvd_prep, dim3(496), dim3(256), 0, stream, U, T, UO, ws32);

  const u16* BTf  = (const u16*)d_ws;         // 204800 u16
  const u16* UcTf = BTf + 204800;             // 32768 u16
  const u16* UOTf = UcTf + 32768;             // 16384 u16

  const int bs = in_sizes[0] / 512;           // (BS,2,256)
  hipLaunchKernelGGL(hosvd_main, dim3(bs / TB), dim3(NTHR), 0, stream,
                     nh, te, bw, Ut, bt, bO, BTf, UcTf, UOTf, out);
}